// Round 1
// baseline (35.375 us; speedup 1.0000x reference)
//
#include <hip/hip_runtime.h>

// Fasttext: out[b,t,p] = W @ embed[ids[b,t]] + b, masked t < seq_lengths[b]
// VOCAB=200000, E=300 (pad->320), P=128, B=16, S=2048, BS=32768

#define VOCAB 200000
#define E 300
#define EP 320          // padded K for MFMA (10 * 32)
#define EPAD 328        // LDS row stride in elements (+8 bf16 = +16B: bank-conflict pad)
#define P 128
#define S 2048
#define BS 32768
#define TM 64           // tokens per block tile

typedef short bf16x8 __attribute__((ext_vector_type(8)));
typedef float f32x4 __attribute__((ext_vector_type(4)));

__device__ inline unsigned short f32_bf16_rne(float f) {
    unsigned int u = __builtin_bit_cast(unsigned int, f);
    unsigned int r = u + 0x7FFFu + ((u >> 16) & 1u);
    return (unsigned short)(r >> 16);
}

// prep: W [128][300] f32 -> Wb [128][320] bf16, zero-padded K
__global__ void ft_wprep(const float* __restrict__ W, unsigned short* __restrict__ Wb) {
    int i = blockIdx.x * 256 + threadIdx.x;
    if (i >= P * EP) return;
    int p = i / EP, e = i - p * EP;
    float v = (e < E) ? W[p * E + e] : 0.0f;
    Wb[i] = f32_bf16_rne(v);
}

template <bool USE_WS>
__global__ __launch_bounds__(256) void ft_main(
    const int* __restrict__ ids, const int* __restrict__ seqlen,
    const float* __restrict__ embed, const unsigned short* __restrict__ Wb,
    const float* __restrict__ Wf, const float* __restrict__ bias,
    float* __restrict__ out)
{
    __shared__ unsigned short Alds[TM][EPAD];   // 64 x 328 x 2B = 41,984 B -> 3 blocks/CU

    const int tid = threadIdx.x;
    const int wave = tid >> 6, lane = tid & 63;
    const int tok0 = blockIdx.x * TM;

    // ---- full-tile mask early-out (tile lies within one batch: 64 | 2048) ----
    const int bi0 = tok0 >> 11;           // batch of this tile
    const int t0  = tok0 & (S - 1);       // first in-seq position
    const int sl0 = seqlen[bi0];
    if (sl0 <= t0) {
        // entire tile masked: write 64*128 zeros and exit
        f32x4* o = (f32x4*)(out + (long long)tok0 * P);
        f32x4 z = {0.f, 0.f, 0.f, 0.f};
        #pragma unroll
        for (int i = 0; i < (TM * P / 4) / 256; ++i)
            o[tid + i * 256] = z;
        return;
    }

    // ---- stage 64 embed rows -> bf16 LDS (each wave: 16 rows) ----
    #pragma unroll 1
    for (int r = wave * 16; r < wave * 16 + 16; ++r) {
        long long id = ids[tok0 + r];
        const float* row = embed + id * (long long)E;
        #pragma unroll
        for (int it = 0; it < 5; ++it) {
            int e = lane + it * 64;                 // 0..319, coalesced
            float v = (e < E) ? row[e] : 0.0f;
            Alds[r][e] = f32_bf16_rne(v);
        }
    }
    __syncthreads();

    // ---- MFMA: out_tile[64 x 128] = A[64 x 320] * Wb^T ----
    const int wm = wave >> 1, wn = wave & 1;        // 2x2 wave grid
    const int m0 = wm * 32, n0 = wn * 64;           // per-wave 32 x 64
    const int fr = lane & 15, kg = lane >> 4;       // frag row/col, k-group

    f32x4 acc[2][4];
    #pragma unroll
    for (int mi = 0; mi < 2; ++mi)
        #pragma unroll
        for (int ni = 0; ni < 4; ++ni)
            acc[mi][ni] = (f32x4){0.f, 0.f, 0.f, 0.f};

    #pragma unroll
    for (int k0 = 0; k0 < EP; k0 += 32) {
        bf16x8 a[2], b[4];
        #pragma unroll
        for (int mi = 0; mi < 2; ++mi)
            a[mi] = *(const bf16x8*)&Alds[m0 + mi * 16 + fr][k0 + kg * 8];
        #pragma unroll
        for (int ni = 0; ni < 4; ++ni) {
            if constexpr (USE_WS) {
                b[ni] = *(const bf16x8*)&Wb[(n0 + ni * 16 + fr) * EP + k0 + kg * 8];
            } else {
                const float* wr = Wf + (long long)(n0 + ni * 16 + fr) * E;
                #pragma unroll
                for (int j = 0; j < 8; ++j) {
                    int e = k0 + kg * 8 + j;
                    float v = (e < E) ? wr[e] : 0.0f;
                    b[ni][j] = (short)f32_bf16_rne(v);
                }
            }
        }
        #pragma unroll
        for (int mi = 0; mi < 2; ++mi)
            #pragma unroll
            for (int ni = 0; ni < 4; ++ni)
                acc[mi][ni] = __builtin_amdgcn_mfma_f32_16x16x32_bf16(
                    a[mi], b[ni], acc[mi][ni], 0, 0, 0);
    }

    // ---- epilogue: +bias, seq-mask, store ----
    // C/D layout (verified m89): col = lane&15, row = (lane>>4)*4 + j
    #pragma unroll
    for (int mi = 0; mi < 2; ++mi) {
        #pragma unroll
        for (int j = 0; j < 4; ++j) {
            int row = m0 + mi * 16 + kg * 4 + j;
            int token = tok0 + row;
            int t = token & (S - 1);
            int valid = (t < sl0);                   // same batch for whole tile
            #pragma unroll
            for (int ni = 0; ni < 4; ++ni) {
                int p = n0 + ni * 16 + fr;
                float v = acc[mi][ni][j] + bias[p];
                out[(long long)token * P + p] = valid ? v : 0.0f;
            }
        }
    }
}

extern "C" void kernel_launch(void* const* d_in, const int* in_sizes, int n_in,
                              void* d_out, int out_size, void* d_ws, size_t ws_size,
                              hipStream_t stream) {
    const int*   ids    = (const int*)d_in[0];
    const int*   sl     = (const int*)d_in[1];
    const float* embed  = (const float*)d_in[2];
    const float* W      = (const float*)d_in[3];
    const float* bias   = (const float*)d_in[4];
    float*       out    = (float*)d_out;

    const size_t wb_bytes = (size_t)P * EP * 2;
    if (ws_size >= wb_bytes) {
        unsigned short* Wb = (unsigned short*)d_ws;
        ft_wprep<<<(P * EP + 255) / 256, 256, 0, stream>>>(W, Wb);
        ft_main<true><<<BS / TM, 256, 0, stream>>>(ids, sl, embed, Wb, W, bias, out);
    } else {
        ft_main<false><<<BS / TM, 256, 0, stream>>>(ids, sl, embed, nullptr, W, bias, out);
    }
}